// Round 17
// baseline (726.912 us; speedup 1.0000x reference)
//
#include <hip/hip_runtime.h>
#include <hip/hip_cooperative_groups.h>
#include <stdint.h>

namespace cg = cooperative_groups;

// ---------------------------------------------------------------------------
// Binarized CNN (brevitas M5). Activations after bin_act are exactly +/-1,
// weights exactly +/-0.1  ->  layers 2/3/5 + FC are XNOR-popcount convs
// computed EXACTLY in integers. Only conv1 is a real fp32 conv (frozen).
// R17: everything after conv1 (bn_reduce1, signpool, 3x(stats,sign), FC)
// merged into ONE cooperative kernel with grid.sync() between phases --
// R16 showed the bconv kernels are dispatch-overhead dominated (halving
// their inner work moved only 5.6us). 11 dispatches -> 3. All integer /
// BN / rounding code verbatim R16 -> bit-identical output.
// ---------------------------------------------------------------------------

constexpr int Bn  = 64;
constexpr int H1  = 3980;        // conv1 output rows
constexpr int J1  = 1990;        // after pool2x1
constexpr int H2o = 1991, J2 = 995;
constexpr int H3o = 994,  J3 = 497;
constexpr int H5o = 499,  J5 = 249;
constexpr int FCW = 249 * 8;     // u64 words per FC row (512*249 bits)
constexpr int NSH = 16;          // shadow copies for stat atomics
constexpr int QS2 = 0;                       // C=128: 16*128*2 = 4096
constexpr int QS3 = 4096;                    // C=256: 16*256*2 = 8192
constexpr int QS5 = 12288;                   // C=512: 16*512*2 = 16384
constexpr int QS_TOTAL = 28672;
constexpr int MEGA_BLOCKS = 512;

// ------------------------- weight prep (merged) -----------------------------
__global__ __launch_bounds__(256) void prep_all(
    const float* __restrict__ w2, const float* __restrict__ w3,
    const float* __restrict__ w5, const float* __restrict__ wfc,
    const float* __restrict__ w1,
    uint64_t* __restrict__ wb2, uint64_t* __restrict__ wb3,
    uint64_t* __restrict__ wb5, uint64_t* __restrict__ wbf,
    float* __restrict__ w1pk, unsigned long long* __restrict__ qs)
{
    const int bx  = blockIdx.x;
    const int idx = bx * 256 + threadIdx.x;
    if (idx < QS_TOTAL) qs[idx] = 0ull;

    if (bx < 78) {
        if (idx < 1024) {                              // w2: [128][128][4] -> [c][k][wdx]
            int wdx = idx & 1, k = (idx >> 1) & 3, c = idx >> 3;
            uint64_t v = 0;
            for (int ci = 0; ci < 64; ++ci)
                if (w2[((size_t)c * 128 + (wdx * 64 + ci)) * 4 + k] >= 0.f) v |= 1ull << ci;
            wb2[idx] = v;
        } else if (idx < 3072) {                       // w3: [256][128][4]
            int t = idx - 1024;
            int wdx = t & 1, k = (t >> 1) & 3, c = t >> 3;
            uint64_t v = 0;
            for (int ci = 0; ci < 64; ++ci)
                if (w3[((size_t)c * 128 + (wdx * 64 + ci)) * 4 + k] >= 0.f) v |= 1ull << ci;
            wb3[t] = v;
        } else if (idx < 9216) {                       // w5: [512][256][3]
            int t = idx - 3072;
            int wdx = t & 3, k = (t >> 2) % 3, c = t / 12;
            uint64_t v = 0;
            for (int ci = 0; ci < 64; ++ci)
                if (w5[((size_t)c * 256 + (wdx * 64 + ci)) * 3 + k] >= 0.f) v |= 1ull << ci;
            wb5[t] = v;
        } else if (idx < 9216 + 10752) {               // w1pk: [16][21][8][4]
            int t  = idx - 9216;
            int G  = t / 672, r = t % 672;
            int kg = r >> 5;
            int e  = r & 31;
            int u  = e >> 2, jj = e & 3;
            w1pk[t] = (w1[(size_t)(G * 8 + u) * 84 + kg * 4 + jj] >= 0.f) ? 0.1f : -0.1f;
        }
    } else {
        const int t = bx - 78;                         // 0..279
        const int oc = t >> 3, wdx = t & 7;
        const int wave = threadIdx.x >> 6, lane = threadIdx.x & 63;
        const int hh = wave * 64 + lane;
        const bool ok = hh < 249;
        const float* src = wfc + (size_t)oc * 127488 + (size_t)wdx * 64 * 249 + hh;
        uint64_t word = 0;
        #pragma unroll 8
        for (int c = 0; c < 64; ++c) {
            const float v = ok ? src[(size_t)c * 249] : -1.f;
            if (v >= 0.f) word |= 1ull << c;
        }
        if (ok) wbf[(size_t)oc * FCW + (size_t)hh * 8 + wdx] = word;
    }
}

// ------------------------------- conv1 (frozen) -----------------------------
#define ROW_FMA(A, XV) \
    A[u] = fmaf(wv.x, XV.x, A[u]); A[u] = fmaf(wv.y, XV.y, A[u]); \
    A[u] = fmaf(wv.z, XV.z, A[u]); A[u] = fmaf(wv.w, XV.w, A[u]);
#define ROW_STAT(A, HOFF) { \
    const int h = h0 + (HOFF) + tid; \
    if (h < H1) { const float v = A[u] + bv; base[h] = v; \
                  s += (double)v; q += (double)v * v; } }

__global__ __launch_bounds__(256) void conv1_y1(
    const float* __restrict__ x, const float4* __restrict__ w1pk,
    const float* __restrict__ b1, float* __restrict__ y1,
    double2* __restrict__ part)
{
    __shared__ float4 xs4[2068];
    __shared__ float4 wl[336];           // [2 g][21 kg][8 u]
    __shared__ double2 statw[4][16];
    const int n   = blockIdx.y;
    const int bh  = blockIdx.x;
    const int h0  = bh << 11;            // 2048 rows per block
    const int z   = blockIdx.z;          // 16-channel slice
    const int tid = threadIdx.x;
    const int wave = tid >> 6, lane = tid & 63;

    const float4* x4 = (const float4*)x + (size_t)n * 4000;
    for (int i = tid; i < 2068; i += 256) {
        const int gi = h0 + i;
        xs4[i] = (gi < 4000) ? x4[gi] : make_float4(0.f, 0.f, 0.f, 0.f);
    }
    const float4* wsrc = w1pk + (size_t)z * 336;
    for (int i = tid; i < 336; i += 256) wl[i] = wsrc[i];
    __syncthreads();

    for (int g = 0; g < 2; ++g) {
        float a0[8] = {0,0,0,0,0,0,0,0};
        float a1r[8] = {0,0,0,0,0,0,0,0};
        float a2[8] = {0,0,0,0,0,0,0,0};
        float a3[8] = {0,0,0,0,0,0,0,0};
        float a4[8] = {0,0,0,0,0,0,0,0};
        float a5[8] = {0,0,0,0,0,0,0,0};
        float a6[8] = {0,0,0,0,0,0,0,0};
        float a7[8] = {0,0,0,0,0,0,0,0};
        #pragma unroll 3
        for (int kg = 0; kg < 21; ++kg) {
            const float4 xv0 = xs4[tid + kg];
            const float4 xv1 = xs4[tid + 256 + kg];
            const float4 xv2 = xs4[tid + 512 + kg];
            const float4 xv3 = xs4[tid + 768 + kg];
            const float4 xv4 = xs4[tid + 1024 + kg];
            const float4 xv5 = xs4[tid + 1280 + kg];
            const float4 xv6 = xs4[tid + 1536 + kg];
            const float4 xv7 = xs4[tid + 1792 + kg];
            const float4* wk = &wl[(g * 21 + kg) * 8];
            #pragma unroll
            for (int u = 0; u < 8; ++u) {
                const float4 wv = wk[u];             // uniform addr -> broadcast
                ROW_FMA(a0, xv0)
                ROW_FMA(a1r, xv1)
                ROW_FMA(a2, xv2)
                ROW_FMA(a3, xv3)
                ROW_FMA(a4, xv4)
                ROW_FMA(a5, xv5)
                ROW_FMA(a6, xv6)
                ROW_FMA(a7, xv7)
            }
        }
        #pragma unroll
        for (int u = 0; u < 8; ++u) {
            const int c = z * 16 + g * 8 + u;
            const float bv = b1[c];
            float* base = y1 + ((size_t)n * 128 + c) * H1;
            double s = 0.0, q = 0.0;
            ROW_STAT(a0, 0)
            ROW_STAT(a1r, 256)
            ROW_STAT(a2, 512)
            ROW_STAT(a3, 768)
            ROW_STAT(a4, 1024)
            ROW_STAT(a5, 1280)
            ROW_STAT(a6, 1536)
            ROW_STAT(a7, 1792)
            #pragma unroll
            for (int o = 32; o > 0; o >>= 1) {
                s += __shfl_xor(s, o, 64);
                q += __shfl_xor(q, o, 64);
            }
            if (lane == 0) statw[wave][g * 8 + u] = make_double2(s, q);
        }
    }
    __syncthreads();
    if (tid < 16) {
        const double2 p0 = statw[0][tid], p1v = statw[1][tid];
        const double2 p2 = statw[2][tid], p3  = statw[3][tid];
        part[((size_t)((n * 2 + bh) * 8 + z)) * 16 + tid] =
            make_double2(((p0.x + p1v.x) + p2.x) + p3.x,
                         ((p0.y + p1v.y) + p2.y) + p3.y);
    }
}

// ------------------------- mega kernel (cooperative) ------------------------
struct MegaArgs {
    const double2* p1;
    float2* bnp1;
    const float* g1; const float* be1;
    const float* y1;
    uint32_t* a1_32;
    const uint64_t* a1;
    const uint64_t* wb2; const uint64_t* wb3; const uint64_t* wb5;
    const uint64_t* wbf;
    unsigned long long* qs;
    const float* b2; const float* g2; const float* be2;
    const float* b3; const float* g3; const float* be3;
    const float* b5; const float* g5; const float* be5;
    uint64_t* a2; uint64_t* a3; uint64_t* a5;
    float* out;
};

// One bconv phase (stats or sign). NSUB row-subtiles, CSPL channel chunks;
// (COUT/CSPL)*NSUB == 256 threads. All win/wreg indices compile-time.
template<int CINW, int KK, int PAD, int COUT, int NSUB, int CSPL, bool SIGN>
__device__ void bconv_phase(const uint64_t* __restrict__ ain,
                            const uint64_t* __restrict__ wbt,
                            const int HIN, const int HOUT, const int J,
                            const double N, const float* __restrict__ bias,
                            unsigned long long* __restrict__ qs,
                            const float* __restrict__ g, const float* __restrict__ be,
                            uint64_t* __restrict__ aout, ulonglong2* rows2)
{
    constexpr int CPB = COUT / CSPL;
    constexpr int TR  = 64 * NSUB;
    constexpr int WR  = TR + KK - 1;
    constexpr int W   = COUT / 64;
    uint64_t* rows = (uint64_t*)rows2;
    const int tid = threadIdx.x;
    const int sub = tid / CPB;
    const int cl  = tid % CPB;
    const int ntiles = (HOUT + TR - 1) / TR;
    const int nvb = ntiles * CSPL * 64;

    for (int vb = blockIdx.x; vb < nvb; vb += gridDim.x) {
        const int tile  = vb % ntiles;
        const int rest  = vb / ntiles;
        const int chunk = rest % CSPL;
        const int n     = rest / CSPL;
        const int c     = chunk * CPB + cl;
        const int h0    = tile * TR;
        __syncthreads();
        for (int i = tid; i < WR * CINW; i += 256) {
            const int r = h0 - PAD + i / CINW;
            rows[i] = (r >= 0 && r < HIN) ? ain[((size_t)n * HIN + r) * CINW + (i % CINW)] : 0ull;
        }
        __syncthreads();
        uint64_t wreg[KK * CINW];
        #pragma unroll
        for (int i2 = 0; i2 < KK * CINW; ++i2) wreg[i2] = wbt[(size_t)c * KK * CINW + i2];
        int pcw[KK];
        #pragma unroll
        for (int k = 0; k < KK; ++k) {
            int pc = 0;
            #pragma unroll
            for (int wd = 0; wd < CINW; ++wd) pc += __popcll(wreg[k * CINW + wd]);
            pcw[k] = pc;
        }
        const int hb   = h0 + sub * 64;
        const int hmax = min(64, HOUT - hb);
        float2 mi = make_float2(0.f, 0.f);
        float bb = 0.f, gg = 0.f, bbe = 0.f;
        if constexpr (SIGN) {
            long long Sq = 0, Sq2 = 0;
            #pragma unroll
            for (int s = 0; s < NSH; ++s) {
                Sq  += (long long)qs[((size_t)s * COUT + c) * 2 + 0];
                Sq2 += (long long)qs[((size_t)s * COUT + c) * 2 + 1];
            }
            const double bb_d = (double)bias[c];
            const double S  = 0.1 * (double)Sq + N * bb_d;           // sum(y), exact
            const double SS = 0.01 * (double)Sq2 + 0.2 * bb_d * (double)Sq + N * bb_d * bb_d;
            const double mu = S / N;
            const double var = SS / N - mu * mu;
            mi = make_float2((float)mu, (float)(1.0 / sqrt(var + 1e-5)));
            bb = bias[c]; gg = g[c]; bbe = be[c];
        }
        int sq = 0, sq2 = 0;
        int i = 0;
        for (; i + 1 < hmax; i += 2) {
            const int l = sub * 64 + i;
            uint64_t win[(KK + 1) * CINW];
            #pragma unroll
            for (int t2 = 0; t2 < (KK + 1) * CINW / 2; ++t2) {
                const ulonglong2 v = rows2[l * (CINW / 2) + t2];
                win[2 * t2] = v.x; win[2 * t2 + 1] = v.y;
            }
            int X0 = 0, X1 = 0;
            #pragma unroll
            for (int k = 0; k < KK; ++k)
                #pragma unroll
                for (int wd = 0; wd < CINW; ++wd) {
                    X0 += __popcll(win[k * CINW + wd] ^ wreg[k * CINW + wd]);
                    X1 += __popcll(win[(k + 1) * CINW + wd] ^ wreg[k * CINW + wd]);
                }
            int q0 = 64 * CINW * KK - 2 * X0;
            int q1 = 64 * CINW * KK - 2 * X1;
            const int h = hb + i;
            if (h < PAD || h + 1 > HIN + PAD - KK) {
                #pragma unroll
                for (int k = 0; k < KK; ++k) {
                    if (k < PAD - h || k >= HIN + PAD - h)
                        q0 -= 64 * CINW - 2 * pcw[k];
                    if (k < PAD - (h + 1) || k >= HIN + PAD - (h + 1))
                        q1 -= 64 * CINW - 2 * pcw[k];
                }
            }
            if constexpr (SIGN) {
                const float y0  = __fadd_rn(__fmul_rn(0.1f, (float)q0), bb);
                const float y1v = __fadd_rn(__fmul_rn(0.1f, (float)q1), bb);
                const float t0 = __fadd_rn(__fmul_rn(__fmul_rn(__fsub_rn(y0,  mi.x), mi.y), gg), bbe);
                const float t1 = __fadd_rn(__fmul_rn(__fmul_rn(__fsub_rn(y1v, mi.x), mi.y), gg), bbe);
                const uint64_t word = __ballot(t0 >= 0.f) | __ballot(t1 >= 0.f);
                const int j = h >> 1;
                if ((c & 63) == 0 && j < J)
                    aout[((size_t)n * J + j) * W + (c >> 6)] = word;
            } else {
                sq += q0 + q1; sq2 += q0 * q0 + q1 * q1;
            }
        }
        if constexpr (!SIGN) {
            if (i < hmax) {                            // odd tail row (stats only)
                const int l = sub * 64 + i;
                const int h = hb + i;
                int X = 0;
                #pragma unroll
                for (int k = 0; k < KK; ++k)
                    #pragma unroll
                    for (int wd = 0; wd < CINW; ++wd)
                        X += __popcll(rows[(l + k) * CINW + wd] ^ wreg[k * CINW + wd]);
                int q = 64 * CINW * KK - 2 * X;
                if (h < PAD || h > HIN + PAD - KK) {
                    #pragma unroll
                    for (int k = 0; k < KK; ++k)
                        if (k < PAD - h || k >= HIN + PAD - h)
                            q -= 64 * CINW - 2 * pcw[k];
                }
                sq += q; sq2 += q * q;
            }
            const int sh = vb & (NSH - 1);
            atomicAdd(&qs[((size_t)sh * COUT + c) * 2 + 0], (unsigned long long)(long long)sq);
            atomicAdd(&qs[((size_t)sh * COUT + c) * 2 + 1], (unsigned long long)(long long)sq2);
        }
    }
}

__global__ __launch_bounds__(256) void mega(MegaArgs A)
{
    cg::grid_group grid = cg::this_grid();
    __shared__ double sS[128], sQ[128];
    __shared__ float2 smi[128];
    __shared__ float  sgm[128], sbe[128];
    __shared__ ulonglong2 rows2[132];
    const int tid = threadIdx.x;

    // ---- phase 0: stage-1 BN reduce (128 vblocks) ----
    if (blockIdx.x < 128) {
        const int c = blockIdx.x;
        const int z = c >> 4, cl = c & 15;
        if (tid < 128) {
            const double2 p = A.p1[((size_t)(tid * 8 + z)) * 16 + cl];
            sS[tid] = p.x; sQ[tid] = p.y;
        }
        __syncthreads();
        for (int o = 64; o > 0; o >>= 1) {
            if (tid < o) { sS[tid] += sS[tid + o]; sQ[tid] += sQ[tid + o]; }
            __syncthreads();
        }
        if (tid == 0) {
            const double N = (double)Bn * H1;
            const double mu  = sS[0] / N;
            const double var = sQ[0] / N - mu * mu;
            A.bnp1[c] = make_float2((float)mu, (float)(1.0 / sqrt(var + 1e-5)));
        }
    }
    grid.sync();

    // ---- phase 1: stage-1 sign + pool + bitpack (1024 vblocks) ----
    if (tid < 128) { smi[tid] = A.bnp1[tid]; sgm[tid] = A.g1[tid]; sbe[tid] = A.be1[tid]; }
    __syncthreads();
    for (int vb = blockIdx.x; vb < 1024; vb += gridDim.x) {
        const int bx = vb & 7, n = (vb >> 3) & 63, half = vb >> 9;
        const int j2 = bx * 128 + (tid & 127);
        const int sub = tid >> 7;
        if (j2 < 995) {
            const int cbase = half * 64 + sub * 32;
            uint32_t wa = 0, wbv = 0;
            for (int i = 0; i < 32; ++i) {
                const int c = cbase + i;
                const float4 v = *(const float4*)(A.y1 + ((size_t)n * 128 + c) * H1 + 4 * j2);
                const float2 mi = smi[c];
                const float gg = sgm[c], bb = sbe[c];
                const float t0 = __fadd_rn(__fmul_rn(__fmul_rn(__fsub_rn(v.x, mi.x), mi.y), gg), bb);
                const float t1 = __fadd_rn(__fmul_rn(__fmul_rn(__fsub_rn(v.y, mi.x), mi.y), gg), bb);
                const float t2 = __fadd_rn(__fmul_rn(__fmul_rn(__fsub_rn(v.z, mi.x), mi.y), gg), bb);
                const float t3 = __fadd_rn(__fmul_rn(__fmul_rn(__fsub_rn(v.w, mi.x), mi.y), gg), bb);
                if ((t0 >= 0.f) || (t1 >= 0.f)) wa  |= 1u << i;
                if ((t2 >= 0.f) || (t3 >= 0.f)) wbv |= 1u << i;
            }
            const size_t w0 = ((size_t)n * J1 + 2 * j2) * 2 + half;
            A.a1_32[w0 * 2 + sub]       = wa;      // j = 2*j2
            A.a1_32[(w0 + 2) * 2 + sub] = wbv;     // j = 2*j2 + 1
        }
    }
    grid.sync();

    // ---- stage 2 ----
    bconv_phase<2, 4, 2, 128, 2, 1, false>(A.a1, A.wb2, J1, H2o, 0, 0.0, nullptr,
                                           A.qs + QS2, nullptr, nullptr, nullptr, rows2);
    grid.sync();
    bconv_phase<2, 4, 2, 128, 2, 1, true>(A.a1, A.wb2, J1, H2o, J2, (double)Bn * H2o,
                                          A.b2, A.qs + QS2, A.g2, A.be2, A.a2, rows2);
    grid.sync();
    // ---- stage 3 ----
    bconv_phase<2, 4, 1, 256, 1, 1, false>(A.a2, A.wb3, J2, H3o, 0, 0.0, nullptr,
                                           A.qs + QS3, nullptr, nullptr, nullptr, rows2);
    grid.sync();
    bconv_phase<2, 4, 1, 256, 1, 1, true>(A.a2, A.wb3, J2, H3o, J3, (double)Bn * H3o,
                                          A.b3, A.qs + QS3, A.g3, A.be3, A.a3, rows2);
    grid.sync();
    // ---- stage 5 ----
    bconv_phase<4, 3, 2, 512, 1, 2, false>(A.a3, A.wb5, J3, H5o, 0, 0.0, nullptr,
                                           A.qs + QS5, nullptr, nullptr, nullptr, rows2);
    grid.sync();
    bconv_phase<4, 3, 2, 512, 1, 2, true>(A.a3, A.wb5, J3, H5o, J5, (double)Bn * H5o,
                                          A.b5, A.qs + QS5, A.g5, A.be5, A.a5, rows2);
    grid.sync();

    // ---- FC ----
    for (int t = blockIdx.x * 4 + (tid >> 6); t < 64 * 35; t += gridDim.x * 4) {
        const int n = t / 35, oc = t % 35;
        const int lane = tid & 63;
        const uint64_t* arow = A.a5  + (size_t)n  * FCW;
        const uint64_t* wrow = A.wbf + (size_t)oc * FCW;
        int X = 0;
        for (int i = lane; i < FCW; i += 64)
            X += __popcll(arow[i] ^ wrow[i]);
        #pragma unroll
        for (int o = 32; o > 0; o >>= 1) X += __shfl_xor(X, o, 64);
        if (lane == 0) A.out[(size_t)n * 35 + oc] = 0.1f * (float)(127488 - 2 * X);
    }
}

// ---------------------------------------------------------------------------
extern "C" void kernel_launch(void* const* d_in, const int* in_sizes, int n_in,
                              void* d_out, int out_size, void* d_ws, size_t ws_size,
                              hipStream_t stream)
{
    (void)in_sizes; (void)n_in; (void)out_size;
    const float* x   = (const float*)d_in[0];
    const float* w1  = (const float*)d_in[1];
    const float* b1  = (const float*)d_in[2];
    const float* g1  = (const float*)d_in[3];
    const float* be1 = (const float*)d_in[4];
    const float* w2  = (const float*)d_in[5];
    const float* b2  = (const float*)d_in[6];
    const float* g2  = (const float*)d_in[7];
    const float* be2 = (const float*)d_in[8];
    const float* w3  = (const float*)d_in[9];
    const float* b3  = (const float*)d_in[10];
    const float* g3  = (const float*)d_in[11];
    const float* be3 = (const float*)d_in[12];
    const float* w5  = (const float*)d_in[13];
    const float* b5  = (const float*)d_in[14];
    const float* g5  = (const float*)d_in[15];
    const float* be5 = (const float*)d_in[16];
    const float* wfc = (const float*)d_in[17];
    char* ws = (char*)d_ws;

    size_t cur = 0;
    auto take = [&](size_t bytes) {
        size_t r = cur;
        cur = (cur + bytes + 255) & ~(size_t)255;
        return r;
    };
    const size_t off_y1 = take(130416640);             // y1 region (130.4 MB)
    float*    y1  = (float*)(ws + off_y1);
    uint64_t* a1  = (uint64_t*)(ws + take(2037760));
    uint64_t* a2  = (uint64_t*)(ws + take(1018880));
    uint64_t* a3  = (uint64_t*)(ws + take(1017856));
    uint64_t* a5  = (uint64_t*)(ws + take(1019904));
    uint64_t* wb2 = (uint64_t*)(ws + take(8192));
    uint64_t* wb3 = (uint64_t*)(ws + take(16384));
    uint64_t* wb5 = (uint64_t*)(ws + take(49152));
    uint64_t* wbf = (uint64_t*)(ws + take(557760));
    float*    w1pk = (float*)(ws + take(43008));       // signed conv1 weights [16][21][8][4]
    double2*  p1  = (double2*)(ws + take(262144));     // 64*2*8 blocks x 16 double2
    unsigned long long* qs = (unsigned long long*)(ws + take(QS_TOTAL * 8));
    float2*   bnp1 = (float2*)(ws + take(1024));
    if (cur > ws_size) return;   // insufficient workspace -> fail loudly

    hipLaunchKernelGGL(prep_all, dim3(358), dim3(256), 0, stream,
                       w2, w3, w5, wfc, w1, wb2, wb3, wb5, wbf, w1pk, qs);
    hipLaunchKernelGGL(conv1_y1, dim3(2, 64, 8), dim3(256), 0, stream,
                       x, (const float4*)w1pk, b1, y1, p1);

    MegaArgs margs;
    margs.p1 = p1; margs.bnp1 = bnp1; margs.g1 = g1; margs.be1 = be1;
    margs.y1 = y1; margs.a1_32 = (uint32_t*)a1; margs.a1 = a1;
    margs.wb2 = wb2; margs.wb3 = wb3; margs.wb5 = wb5; margs.wbf = wbf;
    margs.qs = qs;
    margs.b2 = b2; margs.g2 = g2; margs.be2 = be2;
    margs.b3 = b3; margs.g3 = g3; margs.be3 = be3;
    margs.b5 = b5; margs.g5 = g5; margs.be5 = be5;
    margs.a2 = a2; margs.a3 = a3; margs.a5 = a5;
    margs.out = (float*)d_out;
    void* kp[] = { &margs };
    hipLaunchCooperativeKernel((const void*)mega, dim3(MEGA_BLOCKS), dim3(256),
                               kp, 0, stream);
}

// Round 18
// 304.148 us; speedup vs baseline: 2.3900x; 2.3900x over previous
//
#include <hip/hip_runtime.h>
#include <stdint.h>

// ---------------------------------------------------------------------------
// Binarized CNN (brevitas M5). Activations after bin_act are exactly +/-1,
// weights exactly +/-0.1  ->  layers 2/3/5 + FC are XNOR-popcount convs
// computed EXACTLY in integers. Only conv1 is a real fp32 conv (frozen at
// R13 shape). R18 = R16 verbatim (best measured: 304.2us). R17's cooperative
// mega-kernel was 630us: grid.sync() costs ~60us each on MI355X (device-scope
// L2 drain across 8 XCDs) vs ~4us per launch gap -- fusion refuted.
// ---------------------------------------------------------------------------

constexpr int Bn  = 64;
constexpr int H1  = 3980;        // conv1 output rows
constexpr int J1  = 1990;        // after pool2x1
constexpr int H2o = 1991, J2 = 995;
constexpr int H3o = 994,  J3 = 497;
constexpr int H5o = 499,  J5 = 249;
constexpr int FCW = 249 * 8;     // u64 words per FC row (512*249 bits)
constexpr int NSH = 16;          // shadow copies for stat atomics
constexpr int QS2 = 0;                       // C=128: 16*128*2 = 4096
constexpr int QS3 = 4096;                    // C=256: 16*256*2 = 8192
constexpr int QS5 = 12288;                   // C=512: 16*512*2 = 16384
constexpr int QS_TOTAL = 28672;

// ------------------------- weight prep (merged) -----------------------------
__global__ __launch_bounds__(256) void prep_all(
    const float* __restrict__ w2, const float* __restrict__ w3,
    const float* __restrict__ w5, const float* __restrict__ wfc,
    const float* __restrict__ w1,
    uint64_t* __restrict__ wb2, uint64_t* __restrict__ wb3,
    uint64_t* __restrict__ wb5, uint64_t* __restrict__ wbf,
    float* __restrict__ w1pk, unsigned long long* __restrict__ qs)
{
    const int bx  = blockIdx.x;
    const int idx = bx * 256 + threadIdx.x;
    if (idx < QS_TOTAL) qs[idx] = 0ull;

    if (bx < 78) {
        if (idx < 1024) {                              // w2: [128][128][4] -> [c][k][wdx]
            int wdx = idx & 1, k = (idx >> 1) & 3, c = idx >> 3;
            uint64_t v = 0;
            for (int ci = 0; ci < 64; ++ci)
                if (w2[((size_t)c * 128 + (wdx * 64 + ci)) * 4 + k] >= 0.f) v |= 1ull << ci;
            wb2[idx] = v;
        } else if (idx < 3072) {                       // w3: [256][128][4]
            int t = idx - 1024;
            int wdx = t & 1, k = (t >> 1) & 3, c = t >> 3;
            uint64_t v = 0;
            for (int ci = 0; ci < 64; ++ci)
                if (w3[((size_t)c * 128 + (wdx * 64 + ci)) * 4 + k] >= 0.f) v |= 1ull << ci;
            wb3[t] = v;
        } else if (idx < 9216) {                       // w5: [512][256][3]
            int t = idx - 3072;
            int wdx = t & 3, k = (t >> 2) % 3, c = t / 12;
            uint64_t v = 0;
            for (int ci = 0; ci < 64; ++ci)
                if (w5[((size_t)c * 256 + (wdx * 64 + ci)) * 3 + k] >= 0.f) v |= 1ull << ci;
            wb5[t] = v;
        } else if (idx < 9216 + 10752) {               // w1pk: [16][21][8][4]
            int t  = idx - 9216;
            int G  = t / 672, r = t % 672;
            int kg = r >> 5;
            int e  = r & 31;
            int u  = e >> 2, jj = e & 3;
            w1pk[t] = (w1[(size_t)(G * 8 + u) * 84 + kg * 4 + jj] >= 0.f) ? 0.1f : -0.1f;
        }
    } else {
        const int t = bx - 78;                         // 0..279
        const int oc = t >> 3, wdx = t & 7;
        const int wave = threadIdx.x >> 6, lane = threadIdx.x & 63;
        const int hh = wave * 64 + lane;
        const bool ok = hh < 249;
        const float* src = wfc + (size_t)oc * 127488 + (size_t)wdx * 64 * 249 + hh;
        uint64_t word = 0;
        #pragma unroll 8
        for (int c = 0; c < 64; ++c) {
            const float v = ok ? src[(size_t)c * 249] : -1.f;
            if (v >= 0.f) word |= 1ull << c;
        }
        if (ok) wbf[(size_t)oc * FCW + (size_t)hh * 8 + wdx] = word;
    }
}

// ------------------------------- conv1 (frozen) -----------------------------
#define ROW_FMA(A, XV) \
    A[u] = fmaf(wv.x, XV.x, A[u]); A[u] = fmaf(wv.y, XV.y, A[u]); \
    A[u] = fmaf(wv.z, XV.z, A[u]); A[u] = fmaf(wv.w, XV.w, A[u]);
#define ROW_STAT(A, HOFF) { \
    const int h = h0 + (HOFF) + tid; \
    if (h < H1) { const float v = A[u] + bv; base[h] = v; \
                  s += (double)v; q += (double)v * v; } }

__global__ __launch_bounds__(256) void conv1_y1(
    const float* __restrict__ x, const float4* __restrict__ w1pk,
    const float* __restrict__ b1, float* __restrict__ y1,
    double2* __restrict__ part)
{
    __shared__ float4 xs4[2068];
    __shared__ float4 wl[336];           // [2 g][21 kg][8 u]
    __shared__ double2 statw[4][16];
    const int n   = blockIdx.y;
    const int bh  = blockIdx.x;
    const int h0  = bh << 11;            // 2048 rows per block
    const int z   = blockIdx.z;          // 16-channel slice
    const int tid = threadIdx.x;
    const int wave = tid >> 6, lane = tid & 63;

    const float4* x4 = (const float4*)x + (size_t)n * 4000;
    for (int i = tid; i < 2068; i += 256) {
        const int gi = h0 + i;
        xs4[i] = (gi < 4000) ? x4[gi] : make_float4(0.f, 0.f, 0.f, 0.f);
    }
    const float4* wsrc = w1pk + (size_t)z * 336;
    for (int i = tid; i < 336; i += 256) wl[i] = wsrc[i];
    __syncthreads();

    for (int g = 0; g < 2; ++g) {
        float a0[8] = {0,0,0,0,0,0,0,0};
        float a1r[8] = {0,0,0,0,0,0,0,0};
        float a2[8] = {0,0,0,0,0,0,0,0};
        float a3[8] = {0,0,0,0,0,0,0,0};
        float a4[8] = {0,0,0,0,0,0,0,0};
        float a5[8] = {0,0,0,0,0,0,0,0};
        float a6[8] = {0,0,0,0,0,0,0,0};
        float a7[8] = {0,0,0,0,0,0,0,0};
        #pragma unroll 3
        for (int kg = 0; kg < 21; ++kg) {
            const float4 xv0 = xs4[tid + kg];
            const float4 xv1 = xs4[tid + 256 + kg];
            const float4 xv2 = xs4[tid + 512 + kg];
            const float4 xv3 = xs4[tid + 768 + kg];
            const float4 xv4 = xs4[tid + 1024 + kg];
            const float4 xv5 = xs4[tid + 1280 + kg];
            const float4 xv6 = xs4[tid + 1536 + kg];
            const float4 xv7 = xs4[tid + 1792 + kg];
            const float4* wk = &wl[(g * 21 + kg) * 8];
            #pragma unroll
            for (int u = 0; u < 8; ++u) {
                const float4 wv = wk[u];             // uniform addr -> broadcast
                ROW_FMA(a0, xv0)
                ROW_FMA(a1r, xv1)
                ROW_FMA(a2, xv2)
                ROW_FMA(a3, xv3)
                ROW_FMA(a4, xv4)
                ROW_FMA(a5, xv5)
                ROW_FMA(a6, xv6)
                ROW_FMA(a7, xv7)
            }
        }
        #pragma unroll
        for (int u = 0; u < 8; ++u) {
            const int c = z * 16 + g * 8 + u;
            const float bv = b1[c];
            float* base = y1 + ((size_t)n * 128 + c) * H1;
            double s = 0.0, q = 0.0;
            ROW_STAT(a0, 0)
            ROW_STAT(a1r, 256)
            ROW_STAT(a2, 512)
            ROW_STAT(a3, 768)
            ROW_STAT(a4, 1024)
            ROW_STAT(a5, 1280)
            ROW_STAT(a6, 1536)
            ROW_STAT(a7, 1792)
            #pragma unroll
            for (int o = 32; o > 0; o >>= 1) {
                s += __shfl_xor(s, o, 64);
                q += __shfl_xor(q, o, 64);
            }
            if (lane == 0) statw[wave][g * 8 + u] = make_double2(s, q);
        }
    }
    __syncthreads();
    if (tid < 16) {
        const double2 p0 = statw[0][tid], p1v = statw[1][tid];
        const double2 p2 = statw[2][tid], p3  = statw[3][tid];
        part[((size_t)((n * 2 + bh) * 8 + z)) * 16 + tid] =
            make_double2(((p0.x + p1v.x) + p2.x) + p3.x,
                         ((p0.y + p1v.y) + p2.y) + p3.y);
    }
}

// Final stage-1 BN reduce: one block per channel; 128 (n,bh) partials each.
__global__ __launch_bounds__(128) void bn_reduce1(const double2* __restrict__ part,
                                                  float2* __restrict__ bnp)
{
    __shared__ double sS[128], sQ[128];
    const int c = blockIdx.x, t = threadIdx.x;
    const int z = c >> 4, cl = c & 15;
    const double2 p = part[((size_t)(t * 8 + z)) * 16 + cl];
    sS[t] = p.x; sQ[t] = p.y;
    __syncthreads();
    for (int o = 64; o > 0; o >>= 1) {
        if (t < o) { sS[t] += sS[t + o]; sQ[t] += sQ[t + o]; }
        __syncthreads();
    }
    if (t == 0) {
        const double N = (double)Bn * H1;
        const double mu  = sS[0] / N;
        const double var = sQ[0] / N - mu * mu;
        bnp[c] = make_float2((float)mu, (float)(1.0 / sqrt(var + 1e-5)));
    }
}

// -------------------- stage-1 sign + pool + bitpack -------------------------
__global__ __launch_bounds__(256) void signpool1_y(
    const float* __restrict__ y1, const float2* __restrict__ bnp,
    const float* __restrict__ g1, const float* __restrict__ be1,
    uint32_t* __restrict__ a1_32)
{
    __shared__ float2 smi[128];
    __shared__ float  sg[128], sbe[128];
    const int n    = blockIdx.y;
    const int half = blockIdx.z;                       // u64 word (channel half)
    const int tid  = threadIdx.x;
    if (tid < 128) { smi[tid] = bnp[tid]; sg[tid] = g1[tid]; sbe[tid] = be1[tid]; }
    __syncthreads();
    const int j2  = blockIdx.x * 128 + (tid & 127);    // pair of row-pairs
    const int sub = tid >> 7;                          // u32 quarter within word
    if (j2 >= 995) return;                             // J1/2 = 995
    const int cbase = half * 64 + sub * 32;
    uint32_t wa = 0, wb = 0;
    for (int i = 0; i < 32; ++i) {
        const int c = cbase + i;
        const float4 v = *(const float4*)(y1 + ((size_t)n * 128 + c) * H1 + 4 * j2);
        const float2 mi = smi[c];
        const float gg = sg[c], bb = sbe[c];
        const float t0 = __fadd_rn(__fmul_rn(__fmul_rn(__fsub_rn(v.x, mi.x), mi.y), gg), bb);
        const float t1 = __fadd_rn(__fmul_rn(__fmul_rn(__fsub_rn(v.y, mi.x), mi.y), gg), bb);
        const float t2 = __fadd_rn(__fmul_rn(__fmul_rn(__fsub_rn(v.z, mi.x), mi.y), gg), bb);
        const float t3 = __fadd_rn(__fmul_rn(__fmul_rn(__fsub_rn(v.w, mi.x), mi.y), gg), bb);
        if ((t0 >= 0.f) || (t1 >= 0.f)) wa |= 1u << i;
        if ((t2 >= 0.f) || (t3 >= 0.f)) wb |= 1u << i;
    }
    const size_t w0 = ((size_t)n * J1 + 2 * j2) * 2 + half;
    a1_32[w0 * 2 + sub]       = wa;        // j = 2*j2
    a1_32[(w0 + 2) * 2 + sub] = wb;        // j = 2*j2 + 1
}

// --------------------------- binary convs ----------------------------------
// Row-PAIR processing: contiguous (KK+1)-row window (ulonglong2 LDS reads)
// serves rows i and i+1; all win/wreg indices compile-time (rule #20).
// Exact pad correction per row. Stats -> u64 shadow atomics (bit-exact).
template<int CINW, int KK, int PAD, int COUT>
__global__ __launch_bounds__(COUT) void bconv_stats(
    const uint64_t* __restrict__ ain, const uint64_t* __restrict__ wb,
    const int HIN, const int HOUT, unsigned long long* __restrict__ qs)
{
    constexpr int RW = 64 + KK - 1;
    __shared__ ulonglong2 rows2[RW * CINW / 2];
    uint64_t* rows = (uint64_t*)rows2;
    const int n  = blockIdx.y;
    const int h0 = blockIdx.x << 6;
    const int c  = threadIdx.x;
    for (int i = c; i < RW * CINW; i += COUT) {
        int r = h0 - PAD + i / CINW;
        rows[i] = (r >= 0 && r < HIN) ? ain[((size_t)n * HIN + r) * CINW + (i % CINW)] : 0ull;
    }
    __syncthreads();
    uint64_t wreg[KK * CINW];
    #pragma unroll
    for (int i = 0; i < KK * CINW; ++i) wreg[i] = wb[(size_t)c * KK * CINW + i];
    int pcw[KK];
    #pragma unroll
    for (int k = 0; k < KK; ++k) {
        int pc = 0;
        #pragma unroll
        for (int wd = 0; wd < CINW; ++wd) pc += __popcll(wreg[k * CINW + wd]);
        pcw[k] = pc;
    }
    int sq = 0, sq2 = 0;
    const int hmax = min(64, HOUT - h0);
    int i = 0;
    for (; i + 1 < hmax; i += 2) {
        uint64_t win[(KK + 1) * CINW];
        #pragma unroll
        for (int t = 0; t < (KK + 1) * CINW / 2; ++t) {
            const ulonglong2 v = rows2[i * (CINW / 2) + t];
            win[2 * t] = v.x; win[2 * t + 1] = v.y;
        }
        int X0 = 0, X1 = 0;
        #pragma unroll
        for (int k = 0; k < KK; ++k)
            #pragma unroll
            for (int wd = 0; wd < CINW; ++wd) {
                X0 += __popcll(win[k * CINW + wd] ^ wreg[k * CINW + wd]);
                X1 += __popcll(win[(k + 1) * CINW + wd] ^ wreg[k * CINW + wd]);
            }
        int q0 = 64 * CINW * KK - 2 * X0;
        int q1 = 64 * CINW * KK - 2 * X1;
        const int h = h0 + i;
        if (h < PAD || h + 1 > HIN + PAD - KK) {
            #pragma unroll
            for (int k = 0; k < KK; ++k) {
                if (k < PAD - h || k >= HIN + PAD - h)
                    q0 -= 64 * CINW - 2 * pcw[k];
                if (k < PAD - (h + 1) || k >= HIN + PAD - (h + 1))
                    q1 -= 64 * CINW - 2 * pcw[k];
            }
        }
        sq += q0 + q1; sq2 += q0 * q0 + q1 * q1;
    }
    if (i < hmax) {                                    // odd tail row (stats only)
        const int h = h0 + i;
        int X = 0;
        #pragma unroll
        for (int k = 0; k < KK; ++k)
            #pragma unroll
            for (int wd = 0; wd < CINW; ++wd)
                X += __popcll(rows[(i + k) * CINW + wd] ^ wreg[k * CINW + wd]);
        int q = 64 * CINW * KK - 2 * X;
        if (h < PAD || h > HIN + PAD - KK) {
            #pragma unroll
            for (int k = 0; k < KK; ++k)
                if (k < PAD - h || k >= HIN + PAD - h)
                    q -= 64 * CINW - 2 * pcw[k];
        }
        sq += q; sq2 += q * q;
    }
    const int sh = (blockIdx.x + blockIdx.y) & (NSH - 1);
    atomicAdd(&qs[((size_t)sh * COUT + c) * 2 + 0], (unsigned long long)(long long)sq);
    atomicAdd(&qs[((size_t)sh * COUT + c) * 2 + 1], (unsigned long long)(long long)sq2);
}

// Pass B: per-thread (mu,inv) from exact u64 totals (verbatim double formula),
// then row-pair q recompute, BN, sign; word = ballot(t0)|ballot(t1) (the pool
// pair) written directly. Odd tail row is pool-dropped (floor) -> skipped.
template<int CINW, int KK, int PAD, int COUT>
__global__ __launch_bounds__(COUT) void bconv_sign(
    const uint64_t* __restrict__ ain, const uint64_t* __restrict__ wb,
    const int HIN, const int HOUT, const int J, const double N,
    const float* __restrict__ bias, const unsigned long long* __restrict__ qs,
    const float* __restrict__ g, const float* __restrict__ be,
    uint64_t* __restrict__ aout)
{
    constexpr int W = COUT / 64;
    constexpr int RW = 64 + KK - 1;
    __shared__ ulonglong2 rows2[RW * CINW / 2];
    uint64_t* rows = (uint64_t*)rows2;
    const int n  = blockIdx.y;
    const int h0 = blockIdx.x << 6;
    const int c  = threadIdx.x;
    for (int i = c; i < RW * CINW; i += COUT) {
        int r = h0 - PAD + i / CINW;
        rows[i] = (r >= 0 && r < HIN) ? ain[((size_t)n * HIN + r) * CINW + (i % CINW)] : 0ull;
    }
    long long Sq = 0, Sq2 = 0;
    #pragma unroll
    for (int s = 0; s < NSH; ++s) {
        Sq  += (long long)qs[((size_t)s * COUT + c) * 2 + 0];
        Sq2 += (long long)qs[((size_t)s * COUT + c) * 2 + 1];
    }
    const double bb_d = (double)bias[c];
    const double S  = 0.1 * (double)Sq + N * bb_d;               // sum(y), exact
    const double SS = 0.01 * (double)Sq2 + 0.2 * bb_d * (double)Sq + N * bb_d * bb_d;
    const double mu = S / N;
    const double var = SS / N - mu * mu;
    const float2 mi = make_float2((float)mu, (float)(1.0 / sqrt(var + 1e-5)));
    __syncthreads();
    uint64_t wreg[KK * CINW];
    #pragma unroll
    for (int i = 0; i < KK * CINW; ++i) wreg[i] = wb[(size_t)c * KK * CINW + i];
    int pcw[KK];
    #pragma unroll
    for (int k = 0; k < KK; ++k) {
        int pc = 0;
        #pragma unroll
        for (int wd = 0; wd < CINW; ++wd) pc += __popcll(wreg[k * CINW + wd]);
        pcw[k] = pc;
    }
    const float bb = bias[c], gg = g[c], bbe = be[c];
    const int wv = c >> 6, lane = c & 63;
    const int hmax = min(64, HOUT - h0);
    for (int i = 0; i + 1 < hmax; i += 2) {
        uint64_t win[(KK + 1) * CINW];
        #pragma unroll
        for (int t = 0; t < (KK + 1) * CINW / 2; ++t) {
            const ulonglong2 v = rows2[i * (CINW / 2) + t];
            win[2 * t] = v.x; win[2 * t + 1] = v.y;
        }
        int X0 = 0, X1 = 0;
        #pragma unroll
        for (int k = 0; k < KK; ++k)
            #pragma unroll
            for (int wd = 0; wd < CINW; ++wd) {
                X0 += __popcll(win[k * CINW + wd] ^ wreg[k * CINW + wd]);
                X1 += __popcll(win[(k + 1) * CINW + wd] ^ wreg[k * CINW + wd]);
            }
        int q0 = 64 * CINW * KK - 2 * X0;
        int q1 = 64 * CINW * KK - 2 * X1;
        const int h = h0 + i;
        if (h < PAD || h + 1 > HIN + PAD - KK) {
            #pragma unroll
            for (int k = 0; k < KK; ++k) {
                if (k < PAD - h || k >= HIN + PAD - h)
                    q0 -= 64 * CINW - 2 * pcw[k];
                if (k < PAD - (h + 1) || k >= HIN + PAD - (h + 1))
                    q1 -= 64 * CINW - 2 * pcw[k];
            }
        }
        const float y0 = __fadd_rn(__fmul_rn(0.1f, (float)q0), bb);
        const float y1v = __fadd_rn(__fmul_rn(0.1f, (float)q1), bb);
        const float t0 = __fadd_rn(__fmul_rn(__fmul_rn(__fsub_rn(y0,  mi.x), mi.y), gg), bbe);
        const float t1 = __fadd_rn(__fmul_rn(__fmul_rn(__fsub_rn(y1v, mi.x), mi.y), gg), bbe);
        const uint64_t word = __ballot(t0 >= 0.f) | __ballot(t1 >= 0.f);
        const int j = h >> 1;
        if (lane == 0 && j < J)
            aout[((size_t)n * J + j) * W + wv] = word;
    }
}

// ------------------------------- FC ----------------------------------------
__global__ void fc_kernel(const uint64_t* __restrict__ a5, const uint64_t* __restrict__ wfcb,
                          float* __restrict__ out)
{
    const int n    = blockIdx.y;
    const int oc   = blockIdx.x * 4 + (threadIdx.x >> 6);
    const int lane = threadIdx.x & 63;
    if (oc >= 35) return;
    const uint64_t* arow = a5   + (size_t)n  * FCW;
    const uint64_t* wrow = wfcb + (size_t)oc * FCW;
    int X = 0;
    for (int i = lane; i < FCW; i += 64)
        X += __popcll(arow[i] ^ wrow[i]);
    for (int o = 32; o > 0; o >>= 1) X += __shfl_xor(X, o, 64);
    if (lane == 0) out[(size_t)n * 35 + oc] = 0.1f * (float)(127488 - 2 * X);
}

// ---------------------------------------------------------------------------
extern "C" void kernel_launch(void* const* d_in, const int* in_sizes, int n_in,
                              void* d_out, int out_size, void* d_ws, size_t ws_size,
                              hipStream_t stream)
{
    (void)in_sizes; (void)n_in; (void)out_size;
    const float* x   = (const float*)d_in[0];
    const float* w1  = (const float*)d_in[1];
    const float* b1  = (const float*)d_in[2];
    const float* g1  = (const float*)d_in[3];
    const float* be1 = (const float*)d_in[4];
    const float* w2  = (const float*)d_in[5];
    const float* b2  = (const float*)d_in[6];
    const float* g2  = (const float*)d_in[7];
    const float* be2 = (const float*)d_in[8];
    const float* w3  = (const float*)d_in[9];
    const float* b3  = (const float*)d_in[10];
    const float* g3  = (const float*)d_in[11];
    const float* be3 = (const float*)d_in[12];
    const float* w5  = (const float*)d_in[13];
    const float* b5  = (const float*)d_in[14];
    const float* g5  = (const float*)d_in[15];
    const float* be5 = (const float*)d_in[16];
    const float* wfc = (const float*)d_in[17];
    char* ws = (char*)d_ws;

    size_t cur = 0;
    auto take = [&](size_t bytes) {
        size_t r = cur;
        cur = (cur + bytes + 255) & ~(size_t)255;
        return r;
    };
    const size_t off_y1 = take(130416640);             // y1 region (130.4 MB)
    float*    y1  = (float*)(ws + off_y1);
    uint64_t* a1  = (uint64_t*)(ws + take(2037760));
    uint64_t* a2  = (uint64_t*)(ws + take(1018880));
    uint64_t* a3  = (uint64_t*)(ws + take(1017856));
    uint64_t* a5  = (uint64_t*)(ws + take(1019904));
    uint64_t* wb2 = (uint64_t*)(ws + take(8192));
    uint64_t* wb3 = (uint64_t*)(ws + take(16384));
    uint64_t* wb5 = (uint64_t*)(ws + take(49152));
    uint64_t* wbf = (uint64_t*)(ws + take(557760));
    float*    w1pk = (float*)(ws + take(43008));       // signed conv1 weights [16][21][8][4]
    double2*  p1  = (double2*)(ws + take(262144));     // 64*2*8 blocks x 16 double2
    unsigned long long* qs = (unsigned long long*)(ws + take(QS_TOTAL * 8));
    float2*   bnp1 = (float2*)(ws + take(1024));
    if (cur > ws_size) return;   // insufficient workspace -> fail loudly

    hipLaunchKernelGGL(prep_all, dim3(358), dim3(256), 0, stream,
                       w2, w3, w5, wfc, w1, wb2, wb3, wb5, wbf, w1pk, qs);
    // stage 1: conv once -> y1[n][c][h] + fused stats; reduce; sign+pool pass
    hipLaunchKernelGGL(conv1_y1, dim3(2, 64, 8), dim3(256), 0, stream,
                       x, (const float4*)w1pk, b1, y1, p1);
    hipLaunchKernelGGL(bn_reduce1, dim3(128), dim3(128), 0, stream, p1, bnp1);
    hipLaunchKernelGGL(signpool1_y, dim3(8, 64, 2), dim3(256), 0, stream,
                       y1, bnp1, g1, be1, (uint32_t*)a1);
    // stage 2: stats (shadow atomics), sign (q never materialized)
    hipLaunchKernelGGL((bconv_stats<2, 4, 2, 128>), dim3(32, 64), dim3(128), 0, stream,
                       a1, wb2, J1, H2o, qs + QS2);
    hipLaunchKernelGGL((bconv_sign<2, 4, 2, 128>), dim3(32, 64), dim3(128), 0, stream,
                       a1, wb2, J1, H2o, J2, (double)Bn * H2o, b2, qs + QS2, g2, be2, a2);
    // stage 3
    hipLaunchKernelGGL((bconv_stats<2, 4, 1, 256>), dim3(16, 64), dim3(256), 0, stream,
                       a2, wb3, J2, H3o, qs + QS3);
    hipLaunchKernelGGL((bconv_sign<2, 4, 1, 256>), dim3(16, 64), dim3(256), 0, stream,
                       a2, wb3, J2, H3o, J3, (double)Bn * H3o, b3, qs + QS3, g3, be3, a3);
    // stage 5
    hipLaunchKernelGGL((bconv_stats<4, 3, 2, 512>), dim3(8, 64), dim3(512), 0, stream,
                       a3, wb5, J3, H5o, qs + QS5);
    hipLaunchKernelGGL((bconv_sign<4, 3, 2, 512>), dim3(8, 64), dim3(512), 0, stream,
                       a3, wb5, J3, H5o, J5, (double)Bn * H5o, b5, qs + QS5, g5, be5, a5);
    // FC
    hipLaunchKernelGGL(fc_kernel, dim3(9, 64), dim3(256), 0, stream,
                       a5, wbf, (float*)d_out);
}